// Round 1
// baseline (256.431 us; speedup 1.0000x reference)
//
#include <hip/hip_runtime.h>
#include <hip/hip_bf16.h>
#include <math.h>

// HyenaFilter2D: reference = y + u*D where y = irfft2(rfft2(pad(u)) * rfft2(pad(k))/(FH*FW)).
// Key facts (see analysis): the Gaussian modulation exp(-0.5*(r^2/delta)^2) with
// delta in [0.1,0.3] kills every kernel tap except r^2 <= 1 (we keep r^2 <= 2, i.e.
// the 3x3 neighborhood of (256,256), for margin: taps at r^2>=2 are < 3e-10).
// The double normalization (rfftn(k)/(FH*FW) then backward-normed irfftn) further
// scales the conv by 1/2^20. So:
//   out[b,c,i,j] = u[b,c,i,j]*D[c] + sum_{di,dj in {-1,0,1}} tap[c,di,dj] * u[b,c,i-256-di,j-256-dj]
// with tap[c,di,dj] = h(256+di,256+dj,c) * scaler(r2,delta_c) / (1024*1024),
// h = MLP(pos-emb) with sin activations, evaluated at just 9 pixels.

#define HDIM 512
#define WDIM 512
#define CDIM 32
#define BDIM 2
#define HW   (HDIM*WDIM)

// ---------------- tap computation: 9 positions x 32 channels ----------------
__global__ void compute_taps_kernel(
    const float* __restrict__ zh,   // [512, 5]
    const float* __restrict__ zw,   // [512, 5]
    const float* __restrict__ W0,   // [10, 64]
    const float* __restrict__ b0,   // [64]
    const float* __restrict__ W1,   // [64, 64]
    const float* __restrict__ b1,   // [64]
    const float* __restrict__ W2,   // [64, 64]
    const float* __restrict__ b2,   // [64]
    const float* __restrict__ Wout, // [64, 32]
    const float* __restrict__ freq, // [64]
    const float* __restrict__ deltas, // [32]
    float* __restrict__ taps)       // [9][32] in ws
{
    int t = threadIdx.x;
    if (t >= 9 * CDIM) return;
    int p = t >> 5;          // 0..8  (position)
    int c = t & 31;          // channel
    int di = p / 3 - 1;      // row offset
    int dj = p % 3 - 1;      // col offset
    int i = 256 + di;
    int j = 256 + dj;

    float z[10];
    #pragma unroll
    for (int e = 0; e < 5; e++) z[e]     = zh[i * 5 + e];
    #pragma unroll
    for (int e = 0; e < 5; e++) z[5 + e] = zw[j * 5 + e];

    float h0[64];
    #pragma unroll 4
    for (int o = 0; o < 64; o++) {
        float acc = b0[o];
        for (int e = 0; e < 10; e++) acc += z[e] * W0[e * 64 + o];
        h0[o] = sinf(freq[o] * acc);
    }
    float h1[64];
    #pragma unroll 4
    for (int o = 0; o < 64; o++) {
        float acc = b1[o];
        for (int e = 0; e < 64; e++) acc += h0[e] * W1[e * 64 + o];
        h1[o] = sinf(freq[o] * acc);
    }
    float h2[64];
    #pragma unroll 4
    for (int o = 0; o < 64; o++) {
        float acc = b2[o];
        for (int e = 0; e < 64; e++) acc += h1[e] * W2[e * 64 + o];
        h2[o] = sinf(freq[o] * acc);
    }
    float ho = 0.0f;
    #pragma unroll 8
    for (int e = 0; e < 64; e++) ho += h2[e] * Wout[e * 32 + c];

    float delta = deltas[c];
    float r2 = (float)(di * di + dj * dj);
    float q = r2 / delta;
    float scaler = expf(-0.5f * q * q) / (delta * 2.5066282746310002f); // sqrt(2*pi)
    taps[p * 32 + c] = ho * scaler * (1.0f / (1024.0f * 1024.0f));
}

// ---------------- main elementwise + 9-tap shifted conv ----------------
__global__ __launch_bounds__(256) void hyena_main_kernel(
    const float* __restrict__ u,    // [B, C, 512, 512]
    const float* __restrict__ D,    // [32]
    const float* __restrict__ taps, // [9][32]
    float* __restrict__ out)        // [B, C, 512, 512]
{
    const int total4 = (BDIM * CDIM * HW) / 4;
    int tid = blockIdx.x * blockDim.x + threadIdx.x;
    int stride = gridDim.x * blockDim.x;

    for (int idx4 = tid; idx4 < total4; idx4 += stride) {
        int idx = idx4 << 2;
        int bc  = idx >> 18;          // / (512*512)
        int rem = idx & (HW - 1);
        int i   = rem >> 9;           // row
        int j0  = rem & 511;          // col (multiple of 4)
        int c   = bc & 31;

        const float4 uv = *reinterpret_cast<const float4*>(u + idx);
        float d = D[c];
        float o0 = uv.x * d, o1 = uv.y * d, o2 = uv.z * d, o3 = uv.w * d;

        if (i >= 255) {
            // load the 9 taps for this channel
            float tp[3][3];
            #pragma unroll
            for (int a = 0; a < 3; a++)
                #pragma unroll
                for (int bb = 0; bb < 3; bb++)
                    tp[a][bb] = taps[(a * 3 + bb) * 32 + c];

            const float* ubase = u + bc * HW;
            int basej = j0 - 257;
            #pragma unroll
            for (int a = 0; a < 3; a++) {
                int si = i - 255 - a;          // i - 256 - (a-1)
                if (si < 0) continue;          // si <= 256 always, only lower guard
                const float* row = ubase + si * WDIM;
                float w[6];
                #pragma unroll
                for (int m = 0; m < 6; m++) {
                    int sj = basej + m;
                    w[m] = (sj >= 0 && sj < WDIM) ? row[sj] : 0.0f;
                }
                #pragma unroll
                for (int bb = 0; bb < 3; bb++) {
                    float t = tp[a][bb];
                    // sj = j - 256 - (bb-1)  ->  window index = lane + 2 - bb
                    o0 += t * w[2 - bb + 0];
                    o1 += t * w[2 - bb + 1];
                    o2 += t * w[2 - bb + 2];
                    o3 += t * w[2 - bb + 3];
                }
            }
        }

        *reinterpret_cast<float4*>(out + idx) = make_float4(o0, o1, o2, o3);
    }
}

extern "C" void kernel_launch(void* const* d_in, const int* in_sizes, int n_in,
                              void* d_out, int out_size, void* d_ws, size_t ws_size,
                              hipStream_t stream) {
    const float* u      = (const float*)d_in[0];
    const float* zh     = (const float*)d_in[1];
    const float* zw     = (const float*)d_in[2];
    const float* W0     = (const float*)d_in[3];
    const float* b0     = (const float*)d_in[4];
    const float* W1     = (const float*)d_in[5];
    const float* b1     = (const float*)d_in[6];
    const float* W2     = (const float*)d_in[7];
    const float* b2     = (const float*)d_in[8];
    const float* Wout   = (const float*)d_in[9];
    const float* freq   = (const float*)d_in[10];
    const float* deltas = (const float*)d_in[11];
    const float* D      = (const float*)d_in[12];
    float* out = (float*)d_out;
    float* taps = (float*)d_ws;   // 9*32 floats

    compute_taps_kernel<<<1, 320, 0, stream>>>(zh, zw, W0, b0, W1, b1, W2, b2,
                                               Wout, freq, deltas, taps);
    hyena_main_kernel<<<2048, 256, 0, stream>>>(u, D, taps, out);
}

// Round 2
// 172.470 us; speedup vs baseline: 1.4868x; 1.4868x over previous
//
#include <hip/hip_runtime.h>
#include <hip/hip_bf16.h>
#include <math.h>

// HyenaFilter2D: reference = y + u*D where y = irfft2(rfft2(pad(u)) * rfft2(pad(k))/(FH*FW)).
// The Gaussian modulation exp(-0.5*(r^2/delta)^2), delta in [0.1,0.3], kills every
// kernel tap except the 3x3 neighborhood of (256,256) (taps at r^2>=4 are < 1e-38).
// The double normalization (rfftn(k)/(FH*FW) then backward-normed irfftn) scales the
// conv by 1/2^20. So:
//   out[b,c,i,j] = u[b,c,i,j]*D[c] + sum_{di,dj} tap[c,di,dj] * u[b,c,i-256-di,j-256-dj]
// Valid shifted indices require i>=255 AND j>=255: the conv only touches the
// bottom-right output quadrant, reading u rows/cols [0,256].

#define HDIM 512
#define WDIM 512
#define CDIM 32
#define BDIM 2
#define HW   (HDIM*WDIM)

// ---------------- tap computation: 9 blocks (positions) x 64 lanes (hidden units) ----
__global__ __launch_bounds__(64) void compute_taps_kernel(
    const float* __restrict__ zh,   // [512, 5]
    const float* __restrict__ zw,   // [512, 5]
    const float* __restrict__ W0,   // [10, 64]
    const float* __restrict__ b0,   // [64]
    const float* __restrict__ W1,   // [64, 64]
    const float* __restrict__ b1,   // [64]
    const float* __restrict__ W2,   // [64, 64]
    const float* __restrict__ b2,   // [64]
    const float* __restrict__ Wout, // [64, 32]
    const float* __restrict__ freq, // [64]
    const float* __restrict__ deltas, // [32]
    float* __restrict__ taps)       // [9][32] in ws
{
    int p = blockIdx.x;      // 0..8 tap position
    int o = threadIdx.x;     // 0..63 hidden unit
    int di = p / 3 - 1;
    int dj = p % 3 - 1;
    int i = 256 + di;
    int j = 256 + dj;

    __shared__ float sh[64];

    float z[10];
    #pragma unroll
    for (int e = 0; e < 5; e++) z[e]     = zh[i * 5 + e];
    #pragma unroll
    for (int e = 0; e < 5; e++) z[5 + e] = zw[j * 5 + e];

    float f = freq[o];

    // layer 0: 10 -> 64
    float acc = b0[o];
    #pragma unroll
    for (int e = 0; e < 10; e++) acc += z[e] * W0[e * 64 + o];
    float h = sinf(f * acc);
    sh[o] = h;
    __syncthreads();

    // layer 1: 64 -> 64
    acc = b1[o];
    #pragma unroll 8
    for (int e = 0; e < 64; e++) acc += sh[e] * W1[e * 64 + o];
    h = sinf(f * acc);
    __syncthreads();
    sh[o] = h;
    __syncthreads();

    // layer 2: 64 -> 64
    acc = b2[o];
    #pragma unroll 8
    for (int e = 0; e < 64; e++) acc += sh[e] * W2[e * 64 + o];
    h = sinf(f * acc);
    __syncthreads();
    sh[o] = h;
    __syncthreads();

    // output layer: 64 -> 32, lanes 0..31 each produce one channel
    if (o < 32) {
        float ho = 0.0f;
        #pragma unroll 8
        for (int e = 0; e < 64; e++) ho += sh[e] * Wout[e * 32 + o];
        float delta = deltas[o];
        float r2 = (float)(di * di + dj * dj);
        float q = r2 / delta;
        float scaler = expf(-0.5f * q * q) / (delta * 2.5066282746310002f);
        taps[p * 32 + o] = ho * scaler * (1.0f / (1024.0f * 1024.0f));
    }
}

// ---------------- main elementwise + 9-tap shifted conv (bottom-right quadrant) ----
__global__ __launch_bounds__(256) void hyena_main_kernel(
    const float* __restrict__ u,    // [B, C, 512, 512]
    const float* __restrict__ D,    // [32]
    const float* __restrict__ taps, // [9][32]
    float* __restrict__ out)        // [B, C, 512, 512]
{
    const int total4 = (BDIM * CDIM * HW) / 4;
    int tid = blockIdx.x * blockDim.x + threadIdx.x;
    int stride = gridDim.x * blockDim.x;

    for (int idx4 = tid; idx4 < total4; idx4 += stride) {
        int idx = idx4 << 2;
        int bc  = idx >> 18;          // / (512*512)
        int rem = idx & (HW - 1);
        int i   = rem >> 9;           // row
        int j0  = rem & 511;          // col (multiple of 4)
        int c   = bc & 31;

        const float4 uv = *reinterpret_cast<const float4*>(u + idx);
        float d = D[c];
        float o0 = uv.x * d, o1 = uv.y * d, o2 = uv.z * d, o3 = uv.w * d;

        // conv contributions exist only for i>=255 and output col >= 255
        // (this float4 group touches cols j0..j0+3, so j0 >= 252)
        if (i >= 255 && j0 >= 252) {
            float tp[3][3];
            #pragma unroll
            for (int a = 0; a < 3; a++)
                #pragma unroll
                for (int bb = 0; bb < 3; bb++)
                    tp[a][bb] = taps[(a * 3 + bb) * 32 + c];

            const float* ubase = u + bc * HW;
            int basej = j0 - 257;     // >= -5; max = 508-257 = 251, +5 = 256 < 512
            #pragma unroll
            for (int a = 0; a < 3; a++) {
                int si = i - 255 - a;          // 0..256; lower guard only
                if (si < 0) continue;
                const float* row = ubase + si * WDIM;
                float w[6];
                #pragma unroll
                for (int m = 0; m < 6; m++) {
                    int sj = basej + m;
                    w[m] = (sj >= 0) ? row[sj] : 0.0f;
                }
                #pragma unroll
                for (int bb = 0; bb < 3; bb++) {
                    float t = tp[a][bb];
                    o0 += t * w[2 - bb + 0];
                    o1 += t * w[2 - bb + 1];
                    o2 += t * w[2 - bb + 2];
                    o3 += t * w[2 - bb + 3];
                }
            }
        }

        *reinterpret_cast<float4*>(out + idx) = make_float4(o0, o1, o2, o3);
    }
}

extern "C" void kernel_launch(void* const* d_in, const int* in_sizes, int n_in,
                              void* d_out, int out_size, void* d_ws, size_t ws_size,
                              hipStream_t stream) {
    const float* u      = (const float*)d_in[0];
    const float* zh     = (const float*)d_in[1];
    const float* zw     = (const float*)d_in[2];
    const float* W0     = (const float*)d_in[3];
    const float* b0     = (const float*)d_in[4];
    const float* W1     = (const float*)d_in[5];
    const float* b1     = (const float*)d_in[6];
    const float* W2     = (const float*)d_in[7];
    const float* b2     = (const float*)d_in[8];
    const float* Wout   = (const float*)d_in[9];
    const float* freq   = (const float*)d_in[10];
    const float* deltas = (const float*)d_in[11];
    const float* D      = (const float*)d_in[12];
    float* out = (float*)d_out;
    float* taps = (float*)d_ws;   // 9*32 floats

    compute_taps_kernel<<<9, 64, 0, stream>>>(zh, zw, W0, b0, W1, b1, W2, b2,
                                              Wout, freq, deltas, taps);
    hyena_main_kernel<<<2048, 256, 0, stream>>>(u, D, taps, out);
}